// Round 8
// baseline (132.435 us; speedup 1.0000x reference)
//
#include <hip/hip_runtime.h>
#include <hip/hip_bf16.h>

typedef unsigned short ushort_t;
typedef unsigned int uint_t;

#define CIN   128
#define COUT  256
#define HH    56
#define WW    56
#define HWSZ  3136            // 56*56
#define BATCH 16
#define NPIX  50176           // 16*3136
#define KTOT  1152            // 128*9

// LDS input patch: 3 input rows (y0-1..y0+1) x 58 x-cells (halo) x 128 ci, + 9 pad
// cells for the j=3 tail lanes (x 56..63, results discarded).
// cell stride = 136 ushorts (68 uints): 16B-aligned, bank stride 4 -> 2-way (free).
#define PROW_U  68                    // uints per cell
#define PATCH_U ((3 * 58 + 9) * 68)   // 12444 uints = 49776 B -> 3 blocks/CU

typedef __attribute__((ext_vector_type(8))) short bf16x8;
typedef __attribute__((ext_vector_type(4))) float f32x4;

__device__ __forceinline__ ushort_t f2bf(float v) {
    union { float f; uint_t u; } c; c.f = v;
    uint_t u = c.u;
    u += 0x7FFFu + ((u >> 16) & 1u);   // RNE; inputs finite
    return (ushort_t)(u >> 16);
}

__device__ __forceinline__ uint_t pk2bf(float lo, float hi) {
    __hip_bfloat162 h = __float22bfloat162_rn(make_float2(lo, hi));  // x->low ushort
    union { __hip_bfloat162 h; uint_t u; } c; c.h = h;
    return c.u;
}

// ---- weight prep: OIHW fp32 -> A2 fragment-order table (one co per block).
// A2[((mt*36+s)*4+i)*64 + quad*16 + l16] (ushort8) = W[co=mt*64+i*16+l16][k=s*32+quad*8..+8]
__global__ __launch_bounds__(256) void wprep(
    const float* __restrict__ weights, ushort_t* __restrict__ A2)
{
    __shared__ ushort_t lds_s[KTOT];
    const int tid = threadIdx.x;
    const int co  = blockIdx.x;
    const float* src = weights + (size_t)co * KTOT;
    #pragma unroll
    for (int k = 0; k < 5; ++k) {
        int idx = tid + k * 256;
        if (idx < KTOT) {
            int ci  = idx / 9;
            int pos = idx - ci * 9;
            lds_s[pos * 128 + ci] = f2bf(src[idx]);   // coalesced fp32 read
        }
    }
    __syncthreads();
    int mt  = co >> 6;
    int ii  = (co >> 4) & 3;
    int l16 = co & 15;
    if (tid < 144) {
        int s    = tid >> 2;
        int quad = tid & 3;
        uint4 v = *(const uint4*)&lds_s[(s >> 2) * 128 + (s & 3) * 32 + quad * 8];
        *(uint4*)(A2 + ((size_t)((mt * 36 + s) * 4 + ii) * 64 + quad * 16 + l16) * 8) = v;
    }
}

// ---- direct conv: block = 256co x 56px (ONE output row), 4 waves (64co x 64px tile,
// last 8 px discarded). 3-row LDS patch, single barrier, barrier-free unrolled
// 36-step K-loop (global A-frag dbuf + single-base-VGPR LDS B reads + MFMA).
// Grid 896 (3.5 blocks/CU, 3 co-resident) -> cross-block phase overlap.
__global__ __launch_bounds__(256, 3) void conv_direct(
    const ushort_t* __restrict__ A2,
    const float* __restrict__ tensor,
    const float* __restrict__ bias,
    float* __restrict__ out)
{
    __shared__ __align__(16) uint_t patch[PATCH_U];
    const int tid  = threadIdx.x;
    const int wave = tid >> 6;
    const int lane = tid & 63;
    const int quad = lane >> 4;
    const int l16  = lane & 15;

    const int bn = blockIdx.x;            // [0,896): 56 blocks per image
    const int b  = bn / 56;
    const int y0 = bn - b * 56;           // output row

    const uint4 z4 = make_uint4(0u, 0u, 0u, 0u);
    // ---- zero halo columns (cells x=0 and x=57, slots 0..2): 6 cells x 17 uint4 ----
    if (tid < 102) {
        int cell = tid / 17, part = tid - cell * 17;
        int sl = cell >> 1, xc = (cell & 1) * 57;
        *(uint4*)&patch[(sl * 58 + xc) * PROW_U + part * 4] = z4;
    }
    // ---- zero invalid-row interiors (wave-uniform, rare: 32 of 896 blocks) ----
    if (y0 == 0) {                        // slot0 (y=-1) invalid
        for (int t = tid; t < 952; t += 256) {      // 56 cells x 17 uint4
            int cell = t / 17, part = t - cell * 17;
            *(uint4*)&patch[(cell + 1) * PROW_U + part * 4] = z4;
        }
    }
    if (y0 == 55) {                       // slot2 (y=56) invalid
        for (int t = tid; t < 952; t += 256) {
            int cell = t / 17, part = t - cell * 17;
            *(uint4*)&patch[(2 * 58 + cell + 1) * PROW_U + part * 4] = z4;
        }
    }

    // ---- stage rows y0-1..y0+1 (fp32 NCHW -> bf16 patch), coalesced 224B segments ----
    const float* src_b = tensor + (size_t)b * CIN * HWSZ;
    for (int it = 0; it < 12; ++it) {
        int t  = it * 256 + tid;          // [0,3072); each 256-chunk is one row (wave-uniform y)
        int r  = t >> 10;                 // slot 0..2
        int u  = t & 1023;
        int cp = u >> 4;                  // ci-pair [0,64)
        int xq = u & 15;                  // x-quad; <14 active
        int y  = y0 - 1 + r;
        if (xq < 14 && (uint_t)y < (uint_t)HH) {
            const float* s0 = src_b + (size_t)(2 * cp) * HWSZ + y * WW + xq * 4;
            float4 va = *(const float4*)s0;
            float4 vb = *(const float4*)(s0 + HWSZ);
            uint_t* dst = &patch[(r * 58 + xq * 4 + 1) * PROW_U + cp];
            dst[0 * PROW_U] = pk2bf(va.x, vb.x);
            dst[1 * PROW_U] = pk2bf(va.y, vb.y);
            dst[2 * PROW_U] = pk2bf(va.z, vb.z);
            dst[3 * PROW_U] = pk2bf(va.w, vb.w);
        }
    }
    __syncthreads();      // the ONLY barrier

    // ---- K-loop: B address = ONE reg base + compile-time offsets ----
    const ushort_t* patch_s = (const ushort_t*)patch;
    const int bbase = l16 * 136 + quad * 8;   // cell x = j*16+l16 handled by +j*2176
    const ushort_t* aBase = A2 + ((size_t)(wave * 144) * 64 + lane) * 8;

    const f32x4 zero = {0.f, 0.f, 0.f, 0.f};
    f32x4 acc[4][4];
    #pragma unroll
    for (int i = 0; i < 4; ++i)
        #pragma unroll
        for (int j = 0; j < 4; ++j) acc[i][j] = zero;

    bf16x8 aCur[4], aNxt[4];
    #pragma unroll
    for (int i = 0; i < 4; ++i) aCur[i] = *(const bf16x8*)(aBase + i * 512);

    #pragma unroll
    for (int s = 0; s < 36; ++s) {
        if (s < 35) {
            #pragma unroll
            for (int i = 0; i < 4; ++i)
                aNxt[i] = *(const bf16x8*)(aBase + (size_t)((s + 1) * 4 + i) * 512);
        }
        const int pos = s >> 2;
        const int cc  = s & 3;
        const int off = ((pos / 3) * 58 + (pos % 3)) * 136 + cc * 32;  // compile-time
        #pragma unroll
        for (int j = 0; j < 4; ++j) {
            bf16x8 bf = *(const bf16x8*)&patch_s[bbase + j * 2176 + off];
            #pragma unroll
            for (int i = 0; i < 4; ++i)
                acc[i][j] = __builtin_amdgcn_mfma_f32_16x16x32_bf16(
                    aCur[i], bf, acc[i][j], 0, 0, 0);
        }
        if (s < 35) {
            #pragma unroll
            for (int i = 0; i < 4; ++i) aCur[i] = aNxt[i];   // renamed away under unroll
        }
    }

    // ---- epilogue: row(quad*4+r)=cout, col(l16)=pixel x (64B segments); x>=56 dropped ----
    const size_t rowbase = (size_t)b * (COUT * HWSZ) + y0 * WW;
    #pragma unroll
    for (int i = 0; i < 4; ++i) {
        #pragma unroll
        for (int r = 0; r < 4; ++r) {
            int co = wave * 64 + i * 16 + quad * 4 + r;
            float bv = bias[co];
            size_t obase = rowbase + (size_t)co * HWSZ;
            #pragma unroll
            for (int j = 0; j < 3; ++j)
                out[obase + j * 16 + l16] = acc[i][j][r] + bv;
            if (l16 < 8)                                   // j=3: x=48..55 only
                out[obase + 48 + l16] = acc[i][3][r] + bv;
        }
    }
}

// ---- fallback (only if workspace is too small): direct fp32 conv
__global__ void naive_conv(const float* __restrict__ in, const float* __restrict__ w,
                           const float* __restrict__ bias, float* __restrict__ out, int total) {
    int idx = blockIdx.x * 256 + threadIdx.x;
    if (idx >= total) return;
    int x = idx % WW; int t = idx / WW;
    int y = t % HH; t /= HH;
    int co = t % COUT; int b = t / COUT;
    float s = bias[co];
    const float* wr = w + (size_t)co * KTOT;
    for (int ci = 0; ci < CIN; ++ci) {
        const float* ir = in + (size_t)(b * CIN + ci) * HWSZ;
        for (int kh = 0; kh < 3; ++kh) {
            int yy = y + kh - 1;
            if ((uint_t)yy >= (uint_t)HH) continue;
            for (int kw = 0; kw < 3; ++kw) {
                int xx = x + kw - 1;
                if ((uint_t)xx >= (uint_t)WW) continue;
                s += ir[yy * WW + xx] * wr[ci * 9 + kh * 3 + kw];
            }
        }
    }
    out[idx] = s;
}

extern "C" void kernel_launch(void* const* d_in, const int* in_sizes, int n_in,
                              void* d_out, int out_size, void* d_ws, size_t ws_size,
                              hipStream_t stream) {
    const float* tensor  = (const float*)d_in[0];
    const float* weights = (const float*)d_in[1];
    const float* bias    = (const float*)d_in[2];
    float* out = (float*)d_out;

    const size_t A2_BYTES = (size_t)COUT * KTOT * 2;   // 589824

    if (ws_size >= A2_BYTES) {
        ushort_t* A2 = (ushort_t*)d_ws;
        wprep<<<COUT, 256, 0, stream>>>(weights, A2);
        conv_direct<<<BATCH * HH, 256, 0, stream>>>(A2, tensor, bias, out);
    } else {
        int total = BATCH * COUT * HWSZ;
        naive_conv<<<(total + 255) / 256, 256, 0, stream>>>(tensor, weights, bias, out, total);
    }
}

// Round 9
// 111.748 us; speedup vs baseline: 1.1851x; 1.1851x over previous
//
#include <hip/hip_runtime.h>
#include <hip/hip_bf16.h>

typedef unsigned short ushort_t;
typedef unsigned int uint_t;

#define CIN   128
#define COUT  256
#define HH    56
#define WW    56
#define HWSZ  3136            // 56*56
#define BATCH 16
#define NPIX  50176           // 16*3136
#define KTOT  1152            // 128*9

// Transposed LDS patch: [slot(4 input rows)][ci-chunk(16 of 8ci)][x(58 incl halo)]
// cells of 8 ushorts (16B). B-frag read: 16 consecutive lanes = 256B contiguous
// -> conflict-free; quad offset = 464 ushorts (bank+8). All read offsets are
// compile-time immediates.
#define CHX     58
#define CH_STR  (CHX * 8)          // 464 ushorts per chunk-row
#define SL_STR  (16 * CH_STR)      // 7424 ushorts per slot
#define PATCH_S (4 * SL_STR)       // 29696 ushorts = 59392 B -> 2 blocks/CU

typedef __attribute__((ext_vector_type(8))) short bf16x8;
typedef __attribute__((ext_vector_type(4))) float f32x4;

__device__ __forceinline__ ushort_t f2bf(float v) {
    union { float f; uint_t u; } c; c.f = v;
    uint_t u = c.u;
    u += 0x7FFFu + ((u >> 16) & 1u);   // RNE; inputs finite
    return (ushort_t)(u >> 16);
}

__device__ __forceinline__ uint_t pk2bf(float lo, float hi) {
    __hip_bfloat162 h = __float22bfloat162_rn(make_float2(lo, hi));  // x->low ushort
    union { __hip_bfloat162 h; uint_t u; } c; c.h = h;
    return c.u;
}

// ---- weight prep: OIHW fp32 -> A2 fragment-order table (one co per block).
__global__ __launch_bounds__(256) void wprep(
    const float* __restrict__ weights, ushort_t* __restrict__ A2)
{
    __shared__ ushort_t lds_s[KTOT];
    const int tid = threadIdx.x;
    const int co  = blockIdx.x;
    const float* src = weights + (size_t)co * KTOT;
    #pragma unroll
    for (int k = 0; k < 5; ++k) {
        int idx = tid + k * 256;
        if (idx < KTOT) {
            int ci  = idx / 9;
            int pos = idx - ci * 9;
            lds_s[pos * 128 + ci] = f2bf(src[idx]);   // coalesced fp32 read
        }
    }
    __syncthreads();
    int mt  = co >> 6;
    int ii  = (co >> 4) & 3;
    int l16 = co & 15;
    if (tid < 144) {
        int s    = tid >> 2;
        int quad = tid & 3;
        uint4 v = *(const uint4*)&lds_s[(s >> 2) * 128 + (s & 3) * 32 + quad * 8];
        *(uint4*)(A2 + ((size_t)((mt * 36 + s) * 4 + ii) * 64 + quad * 16 + l16) * 8) = v;
    }
}

// ---- direct conv: block = 256co x 112px (2 output rows), 4 waves (64co x 112px).
// Conflict-free transposed patch; single barrier; barrier-free unrolled 36-step
// K-loop (global A-frag register dbuf + contiguous ds_read_b128 B + 28 MFMA/step).
__global__ __launch_bounds__(256, 2) void conv_direct(
    const ushort_t* __restrict__ A2,
    const float* __restrict__ tensor,
    const float* __restrict__ bias,
    float* __restrict__ out)
{
    __shared__ __align__(16) ushort_t patch[PATCH_S];
    uint_t* patch_u = (uint_t*)patch;
    const int tid  = threadIdx.x;
    const int wave = tid >> 6;
    const int lane = tid & 63;
    const int quad = lane >> 4;
    const int l16  = lane & 15;

    const int bn = blockIdx.x;            // [0,448): 28 blocks per image
    const int b  = bn / 28;
    const int y0 = (bn - b * 28) * 2;     // first output row

    const uint4 z4 = make_uint4(0u, 0u, 0u, 0u);
    // ---- zero halo columns: cells (slot,chunk, x=0|57): 128 cells x 1 uint4 ----
    if (tid < 128) {
        int sc = tid >> 1;                // slot*16+chunk [0,64)
        int xc = (tid & 1) * 57;
        *(uint4*)&patch_u[(sc * CHX + xc) * 4] = z4;
    }
    // ---- zero invalid-row interiors (rare: y0==0 or y0==54) ----
    if (y0 == 0) {                        // slot 0 (y=-1)
        for (int t = tid; t < 928; t += 256)          // 16*58 cells
            *(uint4*)&patch_u[t * 4] = z4;
    }
    if (y0 == 54) {                       // slot 3 (y=56)
        for (int t = tid; t < 928; t += 256)
            *(uint4*)&patch_u[(3 * 16 * CHX + t) * 4] = z4;
    }

    // ---- stage rows y0-1..y0+2 (fp32 NCHW -> bf16 transposed patch) ----
    const float* src_b = tensor + (size_t)b * CIN * HWSZ;
    #pragma unroll
    for (int it = 0; it < 16; ++it) {
        int xq = tid & 15;
        int t2 = it * 16 + (tid >> 4);    // [0,256)
        int cp = t2 & 63;                 // ci-pair
        int pr = t2 >> 6;                 // slot 0..3
        int y  = y0 - 1 + pr;
        if (xq < 14 && (uint_t)y < (uint_t)HH) {
            const float* s0 = src_b + (size_t)(2 * cp) * HWSZ + y * WW + xq * 4;
            float4 va = *(const float4*)s0;
            float4 vb = *(const float4*)(s0 + HWSZ);
            // chunk c = cp>>2, lane-pair lb = cp&3; x = xq*4+dxi+1
            uint_t* dst = &patch_u[((pr * 16 + (cp >> 2)) * CHX + xq * 4 + 1) * 4 + (cp & 3)];
            dst[0 * 4] = pk2bf(va.x, vb.x);
            dst[1 * 4] = pk2bf(va.y, vb.y);
            dst[2 * 4] = pk2bf(va.z, vb.z);
            dst[3 * 4] = pk2bf(va.w, vb.w);
        }
    }
    __syncthreads();      // the ONLY barrier

    // ---- B-fragment bases: p = j*16+l16; slot/x per lane, quad chunk folded in ----
    int bbase[7];
    #pragma unroll
    for (int j = 0; j < 7; ++j) {
        int p  = j * 16 + l16;            // block-local pixel [0,112)
        int ro = p / 56;
        int x  = p - ro * 56;
        bbase[j] = ro * SL_STR + quad * CH_STR + x * 8;
    }

    // ---- A fragment stream (global, register dbuf) ----
    const ushort_t* aBase = A2 + ((size_t)(wave * 144) * 64 + lane) * 8;

    const f32x4 zero = {0.f, 0.f, 0.f, 0.f};
    f32x4 acc[4][7];
    #pragma unroll
    for (int i = 0; i < 4; ++i)
        #pragma unroll
        for (int j = 0; j < 7; ++j) acc[i][j] = zero;

    bf16x8 aCur[4], aNxt[4];
    #pragma unroll
    for (int i = 0; i < 4; ++i) aCur[i] = *(const bf16x8*)(aBase + i * 512);

    #pragma unroll
    for (int s = 0; s < 36; ++s) {
        if (s < 35) {
            #pragma unroll
            for (int i = 0; i < 4; ++i)
                aNxt[i] = *(const bf16x8*)(aBase + (size_t)((s + 1) * 4 + i) * 512);
        }
        const int pos = s >> 2;
        const int cc  = s & 3;
        // offset: slot += dy+1, chunk += cc*4, x += dx+1  (compile-time, >=0)
        const int off = (pos / 3) * SL_STR + cc * 4 * CH_STR + (pos % 3) * 8;
        #pragma unroll
        for (int j = 0; j < 7; ++j) {
            bf16x8 bf = *(const bf16x8*)&patch[bbase[j] + off];
            #pragma unroll
            for (int i = 0; i < 4; ++i)
                acc[i][j] = __builtin_amdgcn_mfma_f32_16x16x32_bf16(
                    aCur[i], bf, acc[i][j], 0, 0, 0);
        }
        if (s < 35) {
            #pragma unroll
            for (int i = 0; i < 4; ++i) aCur[i] = aNxt[i];   // renamed under unroll
        }
    }

    // ---- epilogue: row(quad*4+r)=cout, col(l16)=pixel (x-contiguous 64B segments) ----
    int opix[7];
    #pragma unroll
    for (int j = 0; j < 7; ++j) {
        int p  = j * 16 + l16;
        int ro = p / 56;
        int x  = p - ro * 56;
        opix[j] = (y0 + ro) * WW + x;
    }
    const size_t bout = (size_t)b * (COUT * HWSZ);
    #pragma unroll
    for (int i = 0; i < 4; ++i) {
        #pragma unroll
        for (int r = 0; r < 4; ++r) {
            int co = wave * 64 + i * 16 + quad * 4 + r;
            float bv = bias[co];
            size_t obase = bout + (size_t)co * HWSZ;
            #pragma unroll
            for (int j = 0; j < 7; ++j)
                out[obase + opix[j]] = acc[i][j][r] + bv;
        }
    }
}

// ---- fallback (only if workspace is too small): direct fp32 conv
__global__ void naive_conv(const float* __restrict__ in, const float* __restrict__ w,
                           const float* __restrict__ bias, float* __restrict__ out, int total) {
    int idx = blockIdx.x * 256 + threadIdx.x;
    if (idx >= total) return;
    int x = idx % WW; int t = idx / WW;
    int y = t % HH; t /= HH;
    int co = t % COUT; int b = t / COUT;
    float s = bias[co];
    const float* wr = w + (size_t)co * KTOT;
    for (int ci = 0; ci < CIN; ++ci) {
        const float* ir = in + (size_t)(b * CIN + ci) * HWSZ;
        for (int kh = 0; kh < 3; ++kh) {
            int yy = y + kh - 1;
            if ((uint_t)yy >= (uint_t)HH) continue;
            for (int kw = 0; kw < 3; ++kw) {
                int xx = x + kw - 1;
                if ((uint_t)xx >= (uint_t)WW) continue;
                s += ir[yy * WW + xx] * wr[ci * 9 + kh * 3 + kw];
            }
        }
    }
    out[idx] = s;
}

extern "C" void kernel_launch(void* const* d_in, const int* in_sizes, int n_in,
                              void* d_out, int out_size, void* d_ws, size_t ws_size,
                              hipStream_t stream) {
    const float* tensor  = (const float*)d_in[0];
    const float* weights = (const float*)d_in[1];
    const float* bias    = (const float*)d_in[2];
    float* out = (float*)d_out;

    const size_t A2_BYTES = (size_t)COUT * KTOT * 2;   // 589824

    if (ws_size >= A2_BYTES) {
        ushort_t* A2 = (ushort_t*)d_ws;
        wprep<<<COUT, 256, 0, stream>>>(weights, A2);
        conv_direct<<<NPIX / 112, 256, 0, stream>>>(A2, tensor, bias, out);
    } else {
        int total = BATCH * COUT * HWSZ;
        naive_conv<<<(total + 255) / 256, 256, 0, stream>>>(tensor, weights, bias, out, total);
    }
}